// Round 2
// baseline (578.505 us; speedup 1.0000x reference)
//
#include <hip/hip_runtime.h>
#include <stdint.h>

#define NN 100000   // nodes
#define NK 10       // sampled neighbors
#define D  256      // hidden dim
#define D2 512      // concat dim
#define MT 64       // nodes per block (M tile)

typedef short bf16x8 __attribute__((ext_vector_type(8)));   // 8 bf16 (4 VGPRs)
typedef float f32x4  __attribute__((ext_vector_type(4)));

__device__ __forceinline__ uint16_t f2bf(float f) {
  uint32_t u = __float_as_uint(f);
  u += 0x7fffu + ((u >> 16) & 1u);   // round-to-nearest-even
  return (uint16_t)(u >> 16);
}
__device__ __forceinline__ uint32_t pack2(float a, float b) {
  return (uint32_t)f2bf(a) | ((uint32_t)f2bf(b) << 16);
}

// ---------------------------------------------------------------------------
// Pack W [512][256] f32 into bf16 B-fragment lane order for
// mfma_f32_16x16x32_bf16: Wp[kstep][ntile][lane][j] = bf16(W[kstep*32+(lane>>4)*8+j]
//                                                         [ntile*16+(lane&15)])
// 16*16*64 = 16384 threads, one 16B fragment chunk each.
// ---------------------------------------------------------------------------
__global__ void pack_w(const float* __restrict__ W, uint16_t* __restrict__ Wp) {
  int idx   = blockIdx.x * blockDim.x + threadIdx.x;  // 0..16383
  int lane  = idx & 63;
  int ntile = (idx >> 6) & 15;
  int kstep = idx >> 10;
  int n  = ntile * 16 + (lane & 15);
  int k0 = kstep * 32 + (lane >> 4) * 8;
  float v[8];
#pragma unroll
  for (int j = 0; j < 8; j++) v[j] = W[(size_t)(k0 + j) * D + n];
  uint4 o;
  o.x = pack2(v[0], v[1]);
  o.y = pack2(v[2], v[3]);
  o.z = pack2(v[4], v[5]);
  o.w = pack2(v[6], v[7]);
  ((uint4*)Wp)[idx] = o;
}

// ---------------------------------------------------------------------------
// Fused SAGE layer: gather+mean -> LDS concat tile (bf16) -> MFMA -> bias/ReLU.
// LDS tile: 64 rows x 512 k bf16 = 64 KB, XOR-swizzled 16B chunks
//   chunk' = chunk ^ (row & 15)  (kills the 16-way A-frag bank conflict).
// IN_BF16: input h is bf16 (intermediate layers); else f32.
// OUT_BF16: output stored bf16 (intermediate) ; else f32 (final).
// ---------------------------------------------------------------------------
template <bool IN_BF16, bool OUT_BF16>
__global__ __launch_bounds__(256, 2) void sage_layer(
    const void* __restrict__ hin_v,
    const int*  __restrict__ adj,     // [NN][NK]
    const uint16_t* __restrict__ Wp,  // packed bf16 W [16][16][64][8]
    const float* __restrict__ bias,   // [D] f32
    void*       __restrict__ hout_v,
    const int relu)
{
  __shared__ uint4 lds4[MT * 64];     // 64 rows * 64 chunks * 16B = 64 KB
  const int t  = threadIdx.x;
  const int m0 = blockIdx.x * MT;

  // ---- phase 1: self rows -> chunks 0..31 (k = 0..255) ----
#pragma unroll
  for (int i = 0; i < 8; i++) {
    int cidx = t + i * 256;           // 0..2047
    int r = cidx >> 5;                // row 0..63
    int c = cidx & 31;                // chunk 0..31 (8 elems each)
    uint4 o = {0u, 0u, 0u, 0u};
    int node = m0 + r;
    if (node < NN) {
      if (IN_BF16) {
        o = *(const uint4*)((const uint16_t*)hin_v + (size_t)node * D + c * 8);
      } else {
        const float4* p = (const float4*)((const float*)hin_v + (size_t)node * D + c * 8);
        float4 v0 = p[0], v1 = p[1];
        o.x = pack2(v0.x, v0.y); o.y = pack2(v0.z, v0.w);
        o.z = pack2(v1.x, v1.y); o.w = pack2(v1.z, v1.w);
      }
    }
    lds4[r * 64 + (c ^ (r & 15))] = o;
  }

  // ---- phase 2: neighbor mean -> chunks 32..63 (k = 256..511) ----
  {
    const int half = t >> 5;          // 0..7
    const int l32  = t & 31;          // 32 lanes cover 256 elems (8 each)
#pragma unroll 1
    for (int i = 0; i < 8; i++) {
      int r = i * 8 + half;
      int node = m0 + r;
      float a0=0.f,a1=0.f,a2=0.f,a3=0.f,a4=0.f,a5=0.f,a6=0.f,a7=0.f;
      if (node < NN) {
#pragma unroll
        for (int k = 0; k < NK; k++) {
          int nb = adj[node * NK + k];
          if (IN_BF16) {
            uint4 v = *(const uint4*)((const uint16_t*)hin_v + (size_t)nb * D + l32 * 8);
            a0 += __uint_as_float(v.x << 16);
            a1 += __uint_as_float(v.x & 0xffff0000u);
            a2 += __uint_as_float(v.y << 16);
            a3 += __uint_as_float(v.y & 0xffff0000u);
            a4 += __uint_as_float(v.z << 16);
            a5 += __uint_as_float(v.z & 0xffff0000u);
            a6 += __uint_as_float(v.w << 16);
            a7 += __uint_as_float(v.w & 0xffff0000u);
          } else {
            const float4* p = (const float4*)((const float*)hin_v + (size_t)nb * D + l32 * 8);
            float4 v0 = p[0], v1 = p[1];
            a0 += v0.x; a1 += v0.y; a2 += v0.z; a3 += v0.w;
            a4 += v1.x; a5 += v1.y; a6 += v1.z; a7 += v1.w;
          }
        }
      }
      const float s = 1.0f / (float)NK;
      uint4 o;
      o.x = pack2(a0 * s, a1 * s);
      o.y = pack2(a2 * s, a3 * s);
      o.z = pack2(a4 * s, a5 * s);
      o.w = pack2(a6 * s, a7 * s);
      int c = 32 + l32;
      lds4[r * 64 + (c ^ (r & 15))] = o;
    }
  }

  __syncthreads();

  // ---- phase 3: GEMM  [64 x 512] @ [512 x 256] ----
  const int w    = t >> 6;   // wave 0..3 -> output cols w*64 .. w*64+63
  const int l    = t & 63;
  const int quad = l >> 4;
  const int l16  = l & 15;

  f32x4 acc[4][4];
#pragma unroll
  for (int mt = 0; mt < 4; mt++)
#pragma unroll
    for (int nt = 0; nt < 4; nt++)
      acc[mt][nt] = (f32x4){0.f, 0.f, 0.f, 0.f};

  const uint4* wp4 = (const uint4*)Wp;

#pragma unroll 2
  for (int ks = 0; ks < 16; ks++) {
    bf16x8 af[4], bfr[4];
#pragma unroll
    for (int mt = 0; mt < 4; mt++) {
      int row = mt * 16 + l16;                 // A: m = lane&15
      int c   = ks * 4 + quad;                 // A: k = quad*8 + j
      af[mt] = *((const bf16x8*)&lds4[row * 64 + (c ^ (row & 15))]);
    }
#pragma unroll
    for (int nt = 0; nt < 4; nt++) {
      bfr[nt] = *((const bf16x8*)&wp4[(ks * 16 + (w * 4 + nt)) * 64 + l]);
    }
#pragma unroll
    for (int mt = 0; mt < 4; mt++)
#pragma unroll
      for (int nt = 0; nt < 4; nt++)
        acc[mt][nt] = __builtin_amdgcn_mfma_f32_16x16x32_bf16(
            af[mt], bfr[nt], acc[mt][nt], 0, 0, 0);
  }

  // ---- epilogue: bias (+ReLU) -> store ----
#pragma unroll
  for (int mt = 0; mt < 4; mt++) {
#pragma unroll
    for (int i = 0; i < 4; i++) {
      int rr = m0 + mt * 16 + quad * 4 + i;    // C/D: row = quad*4 + reg
      if (rr < NN) {
#pragma unroll
        for (int nt = 0; nt < 4; nt++) {
          int col = w * 64 + nt * 16 + l16;    // C/D: col = lane&15
          float v = acc[mt][nt][i] + bias[col];
          if (relu) v = fmaxf(v, 0.0f);
          if (OUT_BF16)
            ((uint16_t*)hout_v)[(size_t)rr * D + col] = f2bf(v);
          else
            ((float*)hout_v)[(size_t)rr * D + col] = v;
        }
      }
    }
  }
}

extern "C" void kernel_launch(void* const* d_in, const int* in_sizes, int n_in,
                              void* d_out, int out_size, void* d_ws, size_t ws_size,
                              hipStream_t stream) {
  const float* x   = (const float*)d_in[0];
  const int*   adj = (const int*)d_in[1];
  const float* W0  = (const float*)d_in[2];
  const float* b0  = (const float*)d_in[3];
  const float* W1  = (const float*)d_in[4];
  const float* b1  = (const float*)d_in[5];
  const float* W2  = (const float*)d_in[6];
  const float* b2  = (const float*)d_in[7];
  float* out = (float*)d_out;

  uint16_t* ws  = (uint16_t*)d_ws;
  uint16_t* Wp0 = ws;                    // 512*256 bf16 = 256 KB each
  uint16_t* Wp1 = Wp0 + D2 * D;
  uint16_t* Wp2 = Wp1 + D2 * D;
  uint16_t* hB  = Wp2 + D2 * D;          // [NN][D] bf16 = 51.2 MB (in ws)
  // hA aliases d_out's first 51.2 MB (d_out is 102.4 MB f32; layer 2 reads hB
  // from ws while overwriting d_out, so no read-write overlap).
  uint16_t* hA  = (uint16_t*)d_out;

  pack_w<<<64, 256, 0, stream>>>(W0, Wp0);
  pack_w<<<64, 256, 0, stream>>>(W1, Wp1);
  pack_w<<<64, 256, 0, stream>>>(W2, Wp2);

  const int grid = (NN + MT - 1) / MT;   // 1563 blocks
  sage_layer<false, true ><<<grid, 256, 0, stream>>>(x,  adj, Wp0, b0, hA,  1);
  sage_layer<true,  true ><<<grid, 256, 0, stream>>>(hA, adj, Wp1, b1, hB,  1);
  sage_layer<true,  false><<<grid, 256, 0, stream>>>(hB, adj, Wp2, b2, out, 0);
}

// Round 3
// 516.123 us; speedup vs baseline: 1.1209x; 1.1209x over previous
//
#include <hip/hip_runtime.h>
#include <stdint.h>

#define NN 100000   // nodes
#define NK 10       // sampled neighbors
#define D  256      // hidden dim
#define D2 512      // concat dim
#define MT 32       // nodes per block (M tile); 100000/32 = 3125 exactly -> no tails

typedef short bf16x8 __attribute__((ext_vector_type(8)));   // 8 bf16 (4 VGPRs)
typedef float f32x4  __attribute__((ext_vector_type(4)));

__device__ __forceinline__ uint16_t f2bf(float f) {
  uint32_t u = __float_as_uint(f);
  u += 0x7fffu + ((u >> 16) & 1u);   // round-to-nearest-even
  return (uint16_t)(u >> 16);
}
__device__ __forceinline__ uint32_t pack2(float a, float b) {
  return (uint32_t)f2bf(a) | ((uint32_t)f2bf(b) << 16);
}

// ---------------------------------------------------------------------------
// Pack W [512][256] f32 into bf16 B-fragment lane order for
// mfma_f32_16x16x32_bf16: Wp[kstep][ntile][lane][j] = bf16(W[kstep*32+(lane>>4)*8+j]
//                                                         [ntile*16+(lane&15)])
// ---------------------------------------------------------------------------
__global__ void pack_w(const float* __restrict__ W, uint16_t* __restrict__ Wp) {
  int idx   = blockIdx.x * blockDim.x + threadIdx.x;  // 0..16383
  int lane  = idx & 63;
  int ntile = (idx >> 6) & 15;
  int kstep = idx >> 10;
  int n  = ntile * 16 + (lane & 15);
  int k0 = kstep * 32 + (lane >> 4) * 8;
  float v[8];
#pragma unroll
  for (int j = 0; j < 8; j++) v[j] = W[(size_t)(k0 + j) * D + n];
  uint4 o;
  o.x = pack2(v[0], v[1]);
  o.y = pack2(v[2], v[3]);
  o.z = pack2(v[4], v[5]);
  o.w = pack2(v[6], v[7]);
  ((uint4*)Wp)[idx] = o;
}

// ---------------------------------------------------------------------------
// Fused SAGE layer: gather+mean -> LDS concat tile (bf16) -> MFMA -> bias/ReLU.
// LDS tile: 32 rows x 512 k bf16 = 32 KB -> 5 blocks/CU (vs 2 at 64 KB).
// XOR swizzle on 16B chunks: chunk' = chunk ^ (row & 15).
// ---------------------------------------------------------------------------
template <bool IN_BF16, bool OUT_BF16>
__global__ __launch_bounds__(256, 5) void sage_layer(
    const void* __restrict__ hin_v,
    const int*  __restrict__ adj,     // [NN][NK]
    const uint16_t* __restrict__ Wp,  // packed bf16 W [16][16][64][8]
    const float* __restrict__ bias,   // [D] f32
    void*       __restrict__ hout_v,
    const int relu)
{
  __shared__ uint4 lds4[MT * 64];     // 32 rows * 64 chunks * 16B = 32 KB
  const int t  = threadIdx.x;
  const int m0 = blockIdx.x * MT;

  // ---- phase 1: self rows -> chunks 0..31 (k = 0..255) ----
#pragma unroll
  for (int i = 0; i < 4; i++) {
    int cidx = t + i * 256;           // 0..1023
    int r = cidx >> 5;                // row 0..31
    int c = cidx & 31;                // chunk 0..31 (8 elems each)
    uint4 o;
    int node = m0 + r;
    if (IN_BF16) {
      o = *(const uint4*)((const uint16_t*)hin_v + (size_t)node * D + c * 8);
    } else {
      const float4* p = (const float4*)((const float*)hin_v + (size_t)node * D + c * 8);
      float4 v0 = p[0], v1 = p[1];
      o.x = pack2(v0.x, v0.y); o.y = pack2(v0.z, v0.w);
      o.z = pack2(v1.x, v1.y); o.w = pack2(v1.z, v1.w);
    }
    lds4[r * 64 + (c ^ (r & 15))] = o;
  }

  // ---- phase 2: neighbor mean -> chunks 32..63 (k = 256..511) ----
  {
    const int half = t >> 5;          // 0..7
    const int l32  = t & 31;          // 32 lanes cover 256 elems (8 each)
#pragma unroll 1
    for (int i = 0; i < 4; i++) {
      int r = i * 8 + half;
      int node = m0 + r;
      float a0=0.f,a1=0.f,a2=0.f,a3=0.f,a4=0.f,a5=0.f,a6=0.f,a7=0.f;
#pragma unroll
      for (int k = 0; k < NK; k++) {
        int nb = adj[node * NK + k];
        if (IN_BF16) {
          uint4 v = *(const uint4*)((const uint16_t*)hin_v + (size_t)nb * D + l32 * 8);
          a0 += __uint_as_float(v.x << 16);
          a1 += __uint_as_float(v.x & 0xffff0000u);
          a2 += __uint_as_float(v.y << 16);
          a3 += __uint_as_float(v.y & 0xffff0000u);
          a4 += __uint_as_float(v.z << 16);
          a5 += __uint_as_float(v.z & 0xffff0000u);
          a6 += __uint_as_float(v.w << 16);
          a7 += __uint_as_float(v.w & 0xffff0000u);
        } else {
          const float4* p = (const float4*)((const float*)hin_v + (size_t)nb * D + l32 * 8);
          float4 v0 = p[0], v1 = p[1];
          a0 += v0.x; a1 += v0.y; a2 += v0.z; a3 += v0.w;
          a4 += v1.x; a5 += v1.y; a6 += v1.z; a7 += v1.w;
        }
      }
      const float s = 1.0f / (float)NK;
      uint4 o;
      o.x = pack2(a0 * s, a1 * s);
      o.y = pack2(a2 * s, a3 * s);
      o.z = pack2(a4 * s, a5 * s);
      o.w = pack2(a6 * s, a7 * s);
      int c = 32 + l32;
      lds4[r * 64 + (c ^ (r & 15))] = o;
    }
  }

  __syncthreads();

  // ---- phase 3: GEMM  [32 x 512] @ [512 x 256] ----
  const int w    = t >> 6;   // wave 0..3 -> output cols w*64 .. w*64+63
  const int l    = t & 63;
  const int quad = l >> 4;
  const int l16  = l & 15;

  f32x4 acc[2][4];
#pragma unroll
  for (int mt = 0; mt < 2; mt++)
#pragma unroll
    for (int nt = 0; nt < 4; nt++)
      acc[mt][nt] = (f32x4){0.f, 0.f, 0.f, 0.f};

  const uint4* wp4 = (const uint4*)Wp;

#pragma unroll 2
  for (int ks = 0; ks < 16; ks++) {
    bf16x8 af[2], bfr[4];
#pragma unroll
    for (int mt = 0; mt < 2; mt++) {
      int row = mt * 16 + l16;                 // A: m = lane&15
      int c   = ks * 4 + quad;                 // A: k = quad*8 + j
      af[mt] = *((const bf16x8*)&lds4[row * 64 + (c ^ (row & 15))]);
    }
#pragma unroll
    for (int nt = 0; nt < 4; nt++) {
      bfr[nt] = *((const bf16x8*)&wp4[(ks * 16 + (w * 4 + nt)) * 64 + l]);
    }
#pragma unroll
    for (int mt = 0; mt < 2; mt++)
#pragma unroll
      for (int nt = 0; nt < 4; nt++)
        acc[mt][nt] = __builtin_amdgcn_mfma_f32_16x16x32_bf16(
            af[mt], bfr[nt], acc[mt][nt], 0, 0, 0);
  }

  // ---- epilogue: bias (+ReLU) -> store ----
#pragma unroll
  for (int mt = 0; mt < 2; mt++) {
#pragma unroll
    for (int i = 0; i < 4; i++) {
      int rr = m0 + mt * 16 + quad * 4 + i;    // C/D: row = quad*4 + reg
#pragma unroll
      for (int nt = 0; nt < 4; nt++) {
        int col = w * 64 + nt * 16 + l16;      // C/D: col = lane&15
        float v = acc[mt][nt][i] + bias[col];
        if (relu) v = fmaxf(v, 0.0f);
        if (OUT_BF16)
          ((uint16_t*)hout_v)[(size_t)rr * D + col] = f2bf(v);
        else
          ((float*)hout_v)[(size_t)rr * D + col] = v;
      }
    }
  }
}

extern "C" void kernel_launch(void* const* d_in, const int* in_sizes, int n_in,
                              void* d_out, int out_size, void* d_ws, size_t ws_size,
                              hipStream_t stream) {
  const float* x   = (const float*)d_in[0];
  const int*   adj = (const int*)d_in[1];
  const float* W0  = (const float*)d_in[2];
  const float* b0  = (const float*)d_in[3];
  const float* W1  = (const float*)d_in[4];
  const float* b1  = (const float*)d_in[5];
  const float* W2  = (const float*)d_in[6];
  const float* b2  = (const float*)d_in[7];
  float* out = (float*)d_out;

  uint16_t* ws  = (uint16_t*)d_ws;
  uint16_t* Wp0 = ws;                    // 512*256 bf16 = 256 KB each
  uint16_t* Wp1 = Wp0 + D2 * D;
  uint16_t* Wp2 = Wp1 + D2 * D;
  uint16_t* hB  = Wp2 + D2 * D;          // [NN][D] bf16 = 51.2 MB (in ws)
  // hA aliases d_out's first 51.2 MB (d_out is 102.4 MB f32; layer 2 reads hB
  // from ws while overwriting d_out, so no read-write overlap).
  uint16_t* hA  = (uint16_t*)d_out;

  pack_w<<<64, 256, 0, stream>>>(W0, Wp0);
  pack_w<<<64, 256, 0, stream>>>(W1, Wp1);
  pack_w<<<64, 256, 0, stream>>>(W2, Wp2);

  const int grid = NN / MT;              // 3125 blocks, exact
  sage_layer<false, true ><<<grid, 256, 0, stream>>>(x,  adj, Wp0, b0, hA,  1);
  sage_layer<true,  true ><<<grid, 256, 0, stream>>>(hA, adj, Wp1, b1, hB,  1);
  sage_layer<true,  false><<<grid, 256, 0, stream>>>(hB, adj, Wp2, b2, out, 0);
}